// Round 3
// baseline (376.198 us; speedup 1.0000x reference)
//
#include <hip/hip_runtime.h>

typedef __bf16 bf16x8 __attribute__((ext_vector_type(8)));
typedef float f32x4 __attribute__((ext_vector_type(4)));
typedef unsigned int u32;

#define SEQ_    2048
#define DM_     1024
#define DI_     2048
#define BATCH_  2
#define MTOT    4096   // BATCH_*SEQ_
#define DSTATE  16
#define DTRANK  64
#define XDBLN   96
#define LCH     64
#define NCH     32     // SEQ_/LCH

__device__ __forceinline__ float bf2f(unsigned short u){ return __uint_as_float(((unsigned)u) << 16); }
__device__ __forceinline__ unsigned short f2bf(float f){
  unsigned u = __float_as_uint(f);
  return (unsigned short)((u + 0x7fffu + ((u >> 16) & 1u)) >> 16);  // RNE
}
__device__ __forceinline__ float silu_f(float v){ return v / (1.f + __expf(-v)); }
__device__ __forceinline__ float softplus_f(float v){ return v > 20.f ? v : log1pf(__expf(v)); }

__device__ __forceinline__ void load_lds16(const void* g, void* l){
  __builtin_amdgcn_global_load_lds((const __attribute__((address_space(1))) u32*)g,
                                   (__attribute__((address_space(3))) u32*)l, 16, 0, 0);
}

// ---------------- fp32 -> bf16 convert (vectorized) ----------------
__global__ __launch_bounds__(256) void k_f2bf(const float* __restrict__ in, unsigned short* __restrict__ out, int n){
  int i = (blockIdx.x*256 + threadIdx.x)*4;
  if (i < n){
    float4 v = *(const float4*)(in + i);
    ushort4 o; o.x = f2bf(v.x); o.y = f2bf(v.y); o.z = f2bf(v.z); o.w = f2bf(v.w);
    *(ushort4*)(out + i) = o;
  }
}

// W_x (96,2048) fp32 -> padded (128,2048) bf16, rows 96..127 zero
__global__ __launch_bounds__(256) void k_wxpad(const float* __restrict__ wx, unsigned short* __restrict__ out){
  int i = (blockIdx.x*256 + threadIdx.x)*4;   // over 128*2048
  int row = i >> 11;
  ushort4 o;
  if (row < 96){
    float4 v = *(const float4*)(wx + i);
    o.x = f2bf(v.x); o.y = f2bf(v.y); o.z = f2bf(v.z); o.w = f2bf(v.w);
  } else { o.x = 0; o.y = 0; o.z = 0; o.w = 0; }
  *(ushort4*)(out + i) = o;
}

// extract x_dbl[:, 0:64] -> bf16 [MTOT][64]
__global__ __launch_bounds__(256) void k_xdt(const float* __restrict__ xdbl, unsigned short* __restrict__ out){
  int i = (blockIdx.x*256 + threadIdx.x)*4;   // over MTOT*64
  int m = i >> 6, k = i & 63;
  float4 v = *(const float4*)(xdbl + (size_t)m*XDBLN + k);
  ushort4 o; o.x = f2bf(v.x); o.y = f2bf(v.y); o.z = f2bf(v.z); o.w = f2bf(v.w);
  *(ushort4*)(out + i) = o;
}

// ---------------- bf16 MFMA GEMM: C[M,N] = A[M,K] * B[N,K]^T ----------------
// m97 structure: 128x128 tile, BK=32, 4 waves (2x2), 16x16x32 MFMA, single-barrier dbuf,
// global_load_lds width=16. A and B fragment loads use the SAME k-mapping -> any
// k-permutation of the HW layout cancels; C/D mapping is the m89-verified one.
// MODE 0: split cols [0,2048)->x bf16, [2048,4096)->silu->sres bf16
// MODE 1: fp32 store cols < nvalid (x_dbl)
// MODE 2: softplus(acc + bias[col]) -> fp32 (dt)
// MODE 3: plain fp32 store (final output)
template<int MODE>
__global__ __launch_bounds__(256) void k_gemm(const unsigned short* __restrict__ A,
                                              const unsigned short* __restrict__ Bw,
                                              int K,
                                              float* __restrict__ oF,
                                              unsigned short* __restrict__ oB0,
                                              unsigned short* __restrict__ oB1,
                                              const float* __restrict__ bias,
                                              int ldo, int nvalid)
{
  __shared__ unsigned short lA[2][128*32];
  __shared__ unsigned short lB[2][128*32];
  const int tid  = threadIdx.x;
  const unsigned short* Ab = A  + (size_t)blockIdx.y * 128 * K;
  const unsigned short* Bb = Bw + (size_t)blockIdx.x * 128 * K;

  const int lane = tid & 63;
  const int wv = tid >> 6;
  const int wm = wv >> 1, wn = wv & 1;   // 2x2 wave grid, each wave 64x64
  const int lr = lane & 15, lg = lane >> 4;

  f32x4 acc[4][4] = {};
  const int nk = K >> 5;
  int cur = 0;

  // prologue stage kt=0 into buf 0
  #pragma unroll
  for (int c = 0; c < 2; ++c){
    int e = (c*256 + tid)*8;            // element index within 128x32 tile
    int r = e >> 5, cl = e & 31;
    load_lds16(Ab + (size_t)r*K + cl, &lA[0][e]);
    load_lds16(Bb + (size_t)r*K + cl, &lB[0][e]);
  }

  for (int kt = 0; kt < nk; ++kt){
    __syncthreads();                    // staged buf[cur] visible; prev buf free
    if (kt + 1 < nk){
      int k0 = (kt + 1) * 32;
      int nb = cur ^ 1;
      #pragma unroll
      for (int c = 0; c < 2; ++c){
        int e = (c*256 + tid)*8;
        int r = e >> 5, cl = e & 31;
        load_lds16(Ab + (size_t)r*K + k0 + cl, &lA[nb][e]);
        load_lds16(Bb + (size_t)r*K + k0 + cl, &lB[nb][e]);
      }
    }
    bf16x8 af[4], bfr[4];
    #pragma unroll
    for (int mi = 0; mi < 4; ++mi)
      af[mi] = *(const bf16x8*)&lA[cur][(wm*64 + mi*16 + lr)*32 + lg*8];
    #pragma unroll
    for (int ni = 0; ni < 4; ++ni)
      bfr[ni] = *(const bf16x8*)&lB[cur][(wn*64 + ni*16 + lr)*32 + lg*8];
    #pragma unroll
    for (int mi = 0; mi < 4; ++mi)
      #pragma unroll
      for (int ni = 0; ni < 4; ++ni)
        acc[mi][ni] = __builtin_amdgcn_mfma_f32_16x16x32_bf16(af[mi], bfr[ni], acc[mi][ni], 0, 0, 0);
    cur ^= 1;
  }

  // epilogue: D row = (lane>>4)*4 + reg, col = lane&15  [m89-verified]
  const int rowB = blockIdx.y*128 + wm*64;
  const int colB = blockIdx.x*128 + wn*64;
  #pragma unroll
  for (int mi = 0; mi < 4; ++mi){
    #pragma unroll
    for (int ni = 0; ni < 4; ++ni){
      int col = colB + ni*16 + lr;
      #pragma unroll
      for (int r = 0; r < 4; ++r){
        int row = rowB + mi*16 + lg*4 + r;
        float v = acc[mi][ni][r];
        if (MODE == 0){
          if (col < DI_) oB0[(size_t)row*DI_ + col] = f2bf(v);
          else           oB1[(size_t)row*DI_ + (col - DI_)] = f2bf(silu_f(v));
        } else if (MODE == 1){
          if (col < nvalid) oF[(size_t)row*ldo + col] = v;
        } else if (MODE == 2){
          oF[(size_t)row*ldo + col] = softplus_f(v + bias[col]);
        } else {
          oF[(size_t)row*ldo + col] = v;
        }
      }
    }
  }
}

// ---------------- depthwise causal conv(4) + SiLU ----------------
__global__ __launch_bounds__(256) void k_conv(const unsigned short* __restrict__ xb, const float* __restrict__ w,
                                              const float* __restrict__ cb, unsigned short* __restrict__ ub)
{
  const int d  = blockIdx.x*256 + threadIdx.x;
  const int t0 = blockIdx.y*64;
  const int b  = blockIdx.z;
  const float w0 = w[d*4+0], w1 = w[d*4+1], w2 = w[d*4+2], w3 = w[d*4+3], bias = cb[d];
  const size_t base = (size_t)(b*SEQ_)*DI_ + d;
  float xm3 = 0.f, xm2 = 0.f, xm1 = 0.f;
  if (t0 > 0){
    xm3 = bf2f(xb[base + (size_t)(t0-3)*DI_]);
    xm2 = bf2f(xb[base + (size_t)(t0-2)*DI_]);
    xm1 = bf2f(xb[base + (size_t)(t0-1)*DI_]);
  }
  for (int t = t0; t < t0 + 64; ++t){
    float xc = bf2f(xb[base + (size_t)t*DI_]);
    float acc = w0*xm3 + w1*xm2 + w2*xm1 + w3*xc + bias;
    ub[base + (size_t)t*DI_] = f2bf(silu_f(acc));
    xm3 = xm2; xm2 = xm1; xm1 = xc;
  }
}

// ---------------- chunked selective scan ----------------
// Pass A: per chunk, local scan from h=0; store final local h and prod(dA)
__global__ __launch_bounds__(256) void k_scanA(const float* __restrict__ dtf, const unsigned short* __restrict__ ub,
                                               const float* __restrict__ xdbl, const float* __restrict__ alog,
                                               float* __restrict__ hloc, float* __restrict__ pprod)
{
  const int d = blockIdx.x*256 + threadIdx.x;
  const int c = blockIdx.y, b = blockIdx.z;
  __shared__ float sB[LCH][DSTATE];
  const size_t rowbase = (size_t)(b*SEQ_ + c*LCH);
  for (int i = threadIdx.x; i < LCH*DSTATE; i += 256){
    int t = i >> 4, n = i & 15;
    sB[t][n] = xdbl[(rowbase + t)*XDBLN + DTRANK + n];
  }
  __syncthreads();
  float a[16], h[16], p[16];
  #pragma unroll
  for (int n = 0; n < 16; ++n){
    a[n] = -__expf(alog[(size_t)d*16 + n]);
    h[n] = 0.f; p[n] = 1.f;
  }
  const size_t base = rowbase*DI_ + d;
  for (int t = 0; t < LCH; ++t){
    float dtv = dtf[base + (size_t)t*DI_];
    float uv  = bf2f(ub[base + (size_t)t*DI_]);
    float du  = dtv*uv;
    #pragma unroll
    for (int n = 0; n < 16; ++n){
      float da = __expf(dtv*a[n]);
      h[n] = da*h[n] + du*sB[t][n];
      p[n] *= da;
    }
  }
  const size_t o = ((size_t)(b*NCH + c)*DI_ + d)*16;
  #pragma unroll
  for (int n = 0; n < 16; ++n){ hloc[o+n] = h[n]; pprod[o+n] = p[n]; }
}

// Pass B: stitch chunk-initial states (sequential over NCH chunks)
__global__ __launch_bounds__(256) void k_scanB(const float* __restrict__ hloc, const float* __restrict__ pprod,
                                               float* __restrict__ hinit)
{
  int i = blockIdx.x*256 + threadIdx.x;  // over BATCH_*DI_*16
  int b = i >> 15;
  int r = i & 32767;
  int d = r >> 4, n = r & 15;
  float H = 0.f;
  for (int c = 0; c < NCH; ++c){
    size_t o = ((size_t)(b*NCH + c)*DI_ + d)*16 + n;
    hinit[o] = H;
    H = pprod[o]*H + hloc[o];
  }
}

// Pass C: re-run scan with correct initial state; fuse y = C*h + D*u, gate, bf16
__global__ __launch_bounds__(256) void k_scanC(const float* __restrict__ dtf, const unsigned short* __restrict__ ub,
                                               const float* __restrict__ xdbl, const float* __restrict__ alog,
                                               const float* __restrict__ hinit, const float* __restrict__ Dvec,
                                               const unsigned short* __restrict__ sresb, unsigned short* __restrict__ yg)
{
  const int d = blockIdx.x*256 + threadIdx.x;
  const int c = blockIdx.y, b = blockIdx.z;
  __shared__ float sBC[LCH][32];   // [t][0..15]=B, [16..31]=C
  const size_t rowbase = (size_t)(b*SEQ_ + c*LCH);
  for (int i = threadIdx.x; i < LCH*32; i += 256){
    int t = i >> 5, j = i & 31;
    sBC[t][j] = xdbl[(rowbase + t)*XDBLN + DTRANK + j];
  }
  __syncthreads();
  float a[16], h[16];
  const size_t o = ((size_t)(b*NCH + c)*DI_ + d)*16;
  #pragma unroll
  for (int n = 0; n < 16; ++n){
    a[n] = -__expf(alog[(size_t)d*16 + n]);
    h[n] = hinit[o + n];
  }
  const float Dd = Dvec[d];
  const size_t base = rowbase*DI_ + d;
  for (int t = 0; t < LCH; ++t){
    float dtv = dtf[base + (size_t)t*DI_];
    float uv  = bf2f(ub[base + (size_t)t*DI_]);
    float du  = dtv*uv;
    float y = 0.f;
    #pragma unroll
    for (int n = 0; n < 16; ++n){
      float da = __expf(dtv*a[n]);
      h[n] = da*h[n] + du*sBC[t][n];
      y += h[n]*sBC[t][16+n];
    }
    y += Dd*uv;
    float g = bf2f(sresb[base + (size_t)t*DI_]);
    yg[base + (size_t)t*DI_] = f2bf(y*g);
  }
}

extern "C" void kernel_launch(void* const* d_in, const int* in_sizes, int n_in,
                              void* d_out, int out_size, void* d_ws, size_t ws_size,
                              hipStream_t stream)
{
  const float* hs    = (const float*)d_in[0];
  const float* Win   = (const float*)d_in[1];
  const float* convw = (const float*)d_in[2];
  const float* convb = (const float*)d_in[3];
  const float* Wx    = (const float*)d_in[4];
  const float* Wdt   = (const float*)d_in[5];
  const float* bdt   = (const float*)d_in[6];
  const float* Alog  = (const float*)d_in[7];
  const float* Dvec  = (const float*)d_in[8];
  const float* Wout  = (const float*)d_in[9];
  float* out = (float*)d_out;

  char* p = (char*)d_ws;
  auto take = [&](size_t bytes) -> char* {
    char* r = p; p += (bytes + 255) & ~(size_t)255; return r;
  };
  unsigned short* hsb   = (unsigned short*)take((size_t)MTOT*DM_*2);
  unsigned short* winb  = (unsigned short*)take((size_t)2*DI_*DM_*2);
  unsigned short* woutb = (unsigned short*)take((size_t)DM_*DI_*2);
  unsigned short* wxpb  = (unsigned short*)take((size_t)128*DI_*2);
  unsigned short* wdtb  = (unsigned short*)take((size_t)DI_*DTRANK*2);
  unsigned short* xb    = (unsigned short*)take((size_t)MTOT*DI_*2);
  unsigned short* sresb = (unsigned short*)take((size_t)MTOT*DI_*2);
  unsigned short* ub    = (unsigned short*)take((size_t)MTOT*DI_*2);
  float*          xdbl  = (float*)take((size_t)MTOT*XDBLN*4);
  unsigned short* xdtb  = (unsigned short*)take((size_t)MTOT*DTRANK*2);
  float*          dtf   = (float*)take((size_t)MTOT*DI_*4);
  float*          hloc  = (float*)take((size_t)BATCH_*NCH*DI_*16*4);
  float*          pprod = (float*)take((size_t)BATCH_*NCH*DI_*16*4);
  float*          hinit = (float*)take((size_t)BATCH_*NCH*DI_*16*4);
  unsigned short* yg    = (unsigned short*)take((size_t)MTOT*DI_*2);
  if ((size_t)(p - (char*)d_ws) > ws_size) return;  // fail loudly via validation, don't corrupt

  // dtype converts
  k_f2bf <<<(MTOT*DM_/4 + 255)/256, 256, 0, stream>>>(hs,  hsb,  MTOT*DM_);
  k_f2bf <<<(2*DI_*DM_/4 + 255)/256, 256, 0, stream>>>(Win, winb, 2*DI_*DM_);
  k_f2bf <<<(DM_*DI_/4 + 255)/256, 256, 0, stream>>>(Wout, woutb, DM_*DI_);
  k_f2bf <<<(DI_*DTRANK/4 + 255)/256, 256, 0, stream>>>(Wdt, wdtb, DI_*DTRANK);
  k_wxpad<<<(128*DI_/4)/256, 256, 0, stream>>>(Wx, wxpb);

  // in-projection: xr = hs @ W_in^T ; split -> x (bf16), silu(res) (bf16)
  k_gemm<0><<<dim3(32, 32), 256, 0, stream>>>(hsb, winb, DM_, nullptr, xb, sresb, nullptr, 0, 0);

  // depthwise conv + silu -> u (bf16)
  k_conv<<<dim3(DI_/256, SEQ_/64, BATCH_), 256, 0, stream>>>(xb, convw, convb, ub);

  // x_dbl = u @ W_x^T (N padded 96->128)
  k_gemm<1><<<dim3(1, 32), 256, 0, stream>>>(ub, wxpb, DI_, xdbl, nullptr, nullptr, nullptr, XDBLN, XDBLN);
  k_xdt<<<(MTOT*DTRANK/4)/256, 256, 0, stream>>>(xdbl, xdtb);

  // dt = softplus(x_dbl[:, :64] @ W_dt^T + b_dt)
  k_gemm<2><<<dim3(16, 32), 256, 0, stream>>>(xdtb, wdtb, DTRANK, dtf, nullptr, nullptr, bdt, DI_, DI_);

  // chunked selective scan
  k_scanA<<<dim3(DI_/256, NCH, BATCH_), 256, 0, stream>>>(dtf, ub, xdbl, Alog, hloc, pprod);
  k_scanB<<<(BATCH_*DI_*16)/256, 256, 0, stream>>>(hloc, pprod, hinit);
  k_scanC<<<dim3(DI_/256, NCH, BATCH_), 256, 0, stream>>>(dtf, ub, xdbl, Alog, hinit, Dvec, sresb, yg);

  // final projection: out = (y * silu(res)) @ W_out^T
  k_gemm<3><<<dim3(DM_/128, 32), 256, 0, stream>>>(yg, woutb, DI_, out, nullptr, nullptr, nullptr, DM_, DM_);
}